// Round 4
// baseline (1624.446 us; speedup 1.0000x reference)
//
#include <hip/hip_runtime.h>
#include <hip/hip_bf16.h>

// Device buffers are FLOAT32 (reference is jnp.float32; harness doc: "float32 ->
// const float*"). R1-R3 NaN/zero signatures confirmed: f32 read as bf16 pairs
// gives random-exponent garbage -> every 4096-dot overflows -> NaN (R1/R2),
// scrubbed to exact-zero output (R3, stub-identical absmax).
// Compute path: convert to bf16 in staging, MFMA bf16, f32 accumulate.

typedef __attribute__((ext_vector_type(8))) short short8_t;
typedef __attribute__((ext_vector_type(8))) __bf16 bf16x8;
typedef __attribute__((ext_vector_type(4))) float f32x4;

#define SEQLEN 2048
#define ATT_SCALE 0.08838834764831845f

__device__ __forceinline__ short f2b(float f) {
  if (!__builtin_isfinite(f)) f = 0.0f;   // diagnostic scrub (no-op when correct)
  union { float f; unsigned u; } v; v.f = f;
  unsigned r = (v.u + 0x7fffu + ((v.u >> 16) & 1u)) >> 16;  // RNE
  return (short)r;
}
__device__ __forceinline__ float sf(float f) {          // scrub for f32 stores
  return __builtin_isfinite(f) ? f : 0.0f;
}
// 8 consecutive f32 -> 8 bf16 (as short8)
__device__ __forceinline__ short8_t cvt8(const float* p) {
  f32x4 a = *(const f32x4*)p;
  f32x4 b = *(const f32x4*)(p + 4);
  short8_t o;
  o[0] = f2b(a[0]); o[1] = f2b(a[1]); o[2] = f2b(a[2]); o[3] = f2b(a[3]);
  o[4] = f2b(b[0]); o[5] = f2b(b[1]); o[6] = f2b(b[2]); o[7] = f2b(b[3]);
  return o;
}

// ---------------------------------------------------------------------------
// C[m][n] = sum_k A[m][k] * W[n][k].  A: MxK (f32 or bf16 per template),
// W: NxK f32, C: f32.  128x128 tile, BK=64, 4 waves, 16x16x32 bf16 MFMA.
// ---------------------------------------------------------------------------
template <bool A_BF16>
__global__ __launch_bounds__(256) void gemm_bt(
    const void* __restrict__ Av, const float* __restrict__ W,
    float* __restrict__ C, int K, int ldc)
{
  __shared__ short As[128 * 64];
  __shared__ short Ws[128 * 64];
  const int tid  = threadIdx.x;
  const int lane = tid & 63;
  const int wid  = tid >> 6;
  const int l15  = lane & 15;
  const int l4   = lane >> 4;
  const int m0 = blockIdx.y * 128;
  const int n0 = blockIdx.x * 128;
  const int wr = (wid >> 1) * 64;
  const int wc = (wid & 1) * 64;
  const int srow = tid >> 3;        // 0..31
  const int scol = (tid & 7) * 8;   // 0..56

  f32x4 acc[4][4] = {};

  for (int k0 = 0; k0 < K; k0 += 64) {
    short8_t va[4], vw[4];
#pragma unroll
    for (int i = 0; i < 4; ++i) {
      int arow = m0 + i * 32 + srow;
      if (A_BF16)
        va[i] = *(const short8_t*)((const short*)Av + (size_t)arow * K + k0 + scol);
      else
        va[i] = cvt8((const float*)Av + (size_t)arow * K + k0 + scol);
      vw[i] = cvt8(W + (size_t)(n0 + i * 32 + srow) * K + k0 + scol);
    }
#pragma unroll
    for (int i = 0; i < 4; ++i) {
      *(short8_t*)&As[(i * 32 + srow) * 64 + scol] = va[i];
      *(short8_t*)&Ws[(i * 32 + srow) * 64 + scol] = vw[i];
    }
    __syncthreads();

#pragma unroll
    for (int kk = 0; kk < 2; ++kk) {
      bf16x8 af[4], wf[4];
#pragma unroll
      for (int m = 0; m < 4; ++m)
        af[m] = *(const bf16x8*)&As[(wr + m * 16 + l15) * 64 + kk * 32 + l4 * 8];
#pragma unroll
      for (int n = 0; n < 4; ++n)
        wf[n] = *(const bf16x8*)&Ws[(wc + n * 16 + l15) * 64 + kk * 32 + l4 * 8];
#pragma unroll
      for (int m = 0; m < 4; ++m)
#pragma unroll
        for (int n = 0; n < 4; ++n)
          acc[m][n] = __builtin_amdgcn_mfma_f32_16x16x32_bf16(af[m], wf[n], acc[m][n], 0, 0, 0);
    }
    __syncthreads();
  }

  // C/D layout: col = lane&15, row = (lane>>4)*4 + reg
#pragma unroll
  for (int m = 0; m < 4; ++m) {
    int rbase = m0 + wr + m * 16 + l4 * 4;
#pragma unroll
    for (int n = 0; n < 4; ++n) {
      int cbase = n0 + wc + n * 16 + l15;
#pragma unroll
      for (int r = 0; r < 4; ++r)
        C[(size_t)(rbase + r) * ldc + cbase] = sf(acc[m][n][r]);
    }
  }
}

// RoPE in place, f32, per-head interleaved pairs. width = row width in floats.
__global__ __launch_bounds__(256) void rope_f32(
    float* __restrict__ q, const float* __restrict__ fc, const float* __restrict__ fs,
    int logw)
{
  size_t idx = ((size_t)blockIdx.x * 256 + threadIdx.x) * 8;
  int t   = (int)(idx >> logw);
  int col = (int)(idx & ((1 << logw) - 1));
  int p0  = (col & 127) >> 1;                 // multiple of 4
  f32x4 a = *(const f32x4*)&q[idx];
  f32x4 b = *(const f32x4*)&q[idx + 4];
  f32x4 cv = *(const f32x4*)&fc[t * 64 + p0];
  f32x4 sv = *(const f32x4*)&fs[t * 64 + p0];
  float x0[8] = {a[0], a[1], a[2], a[3], b[0], b[1], b[2], b[3]};
  float o[8];
#pragma unroll
  for (int i = 0; i < 4; ++i) {
    float xr = x0[2 * i], xi = x0[2 * i + 1];
    float c = cv[i], s = sv[i];
    o[2 * i]     = sf(xr * c - xi * s);
    o[2 * i + 1] = sf(xr * s + xi * c);
  }
  *(f32x4*)&q[idx]     = f32x4{o[0], o[1], o[2], o[3]};
  *(f32x4*)&q[idx + 4] = f32x4{o[4], o[5], o[6], o[7]};
}

// cache_v f32 [2048][8*128] -> Vt bf16 [8][128][2048] via 64x64 LDS tile
__global__ __launch_bounds__(256) void transpose_v(
    const float* __restrict__ cv, short* __restrict__ Vt)
{
  __shared__ short tile[64][72];
  const int t0 = blockIdx.x * 64;
  const int d0 = blockIdx.y * 64;
  const int h  = blockIdx.z;
  const int tid = threadIdx.x;
  const int r = tid >> 3;         // 0..31
  const int c = (tid & 7) * 8;    // 0..56
#pragma unroll
  for (int it = 0; it < 2; ++it) {
    short8_t v = cvt8(&cv[(size_t)(t0 + it * 32 + r) * 1024 + h * 128 + d0 + c]);
    *(short8_t*)&tile[it * 32 + r][c] = v;
  }
  __syncthreads();
#pragma unroll
  for (int it = 0; it < 2; ++it) {
    int dr = it * 32 + r;
    short8_t v;
#pragma unroll
    for (int i = 0; i < 8; ++i) v[i] = tile[c + i][dr];
    *(short8_t*)&Vt[(size_t)(h * 128 + d0 + dr) * SEQLEN + t0 + c] = v;
  }
}

// ---------------------------------------------------------------------------
// Causal flash attention. Grid (32 qtiles, 32 heads), 4 waves/block,
// each wave 16 q-rows, KV tiles of 64 keys. Q/K f32 (converted in-register),
// V bf16 (pre-transposed), O bf16 out.
// ---------------------------------------------------------------------------
__global__ __launch_bounds__(256) void attn_fwd(
    const float* __restrict__ Q,    // [2048][4096] roped
    const float* __restrict__ Kc,   // [2048][8*128] roped
    const short* __restrict__ Vt,   // [8][128][2048] bf16
    short* __restrict__ O)          // [2048][4096] bf16
{
  const int qt  = blockIdx.x;
  const int h   = blockIdx.y;
  const int kvh = h >> 2;
  const int tid = threadIdx.x;
  const int wid = tid >> 6;
  const int lane = tid & 63;
  const int l15 = lane & 15;
  const int l4  = lane >> 4;
  const int q0  = qt * 64 + wid * 16;

  __shared__ short Pl[4][16][72];

  bf16x8 qf[4];
  {
    const float* qp = Q + (size_t)(q0 + l15) * 4096 + h * 128 + l4 * 8;
#pragma unroll
    for (int kc = 0; kc < 4; ++kc) {
      short8_t v = cvt8(qp + kc * 32);
      qf[kc] = *(const bf16x8*)&v;
    }
  }

  f32x4 o[8] = {};
  float mrow[4] = {-1e30f, -1e30f, -1e30f, -1e30f};
  float lrow[4] = {0.f, 0.f, 0.f, 0.f};

  const int kend = q0 + 16;
  for (int kt = 0; kt < kend; kt += 64) {
    f32x4 s[4] = {};
#pragma unroll
    for (int n = 0; n < 4; ++n) {
      const float* kp = Kc + (size_t)(kt + n * 16 + l15) * 1024 + kvh * 128 + l4 * 8;
#pragma unroll
      for (int kc = 0; kc < 4; ++kc) {
        short8_t kv = cvt8(kp + kc * 32);
        s[n] = __builtin_amdgcn_mfma_f32_16x16x32_bf16(qf[kc], *(const bf16x8*)&kv, s[n], 0, 0, 0);
      }
    }
    float p[4][4];
#pragma unroll
    for (int r = 0; r < 4; ++r) {
      int qg = q0 + l4 * 4 + r;
      float mx = -1e30f;
#pragma unroll
      for (int n = 0; n < 4; ++n) {
        int kg = kt + n * 16 + l15;
        float val = (kg <= qg) ? s[n][r] * ATT_SCALE : -1e9f;
        p[n][r] = val;
        mx = fmaxf(mx, val);
      }
      mx = fmaxf(mx, __shfl_xor(mx, 1, 64));
      mx = fmaxf(mx, __shfl_xor(mx, 2, 64));
      mx = fmaxf(mx, __shfl_xor(mx, 4, 64));
      mx = fmaxf(mx, __shfl_xor(mx, 8, 64));
      float mnew = fmaxf(mrow[r], mx);
      float resc = __expf(mrow[r] - mnew);
      mrow[r] = mnew;
      float psum = 0.f;
#pragma unroll
      for (int n = 0; n < 4; ++n) {
        float e = __expf(p[n][r] - mnew);
        p[n][r] = e;
        psum += e;
      }
      lrow[r] = lrow[r] * resc + psum;
#pragma unroll
      for (int dt = 0; dt < 8; ++dt) o[dt][r] *= resc;
    }
#pragma unroll
    for (int n = 0; n < 4; ++n)
#pragma unroll
      for (int r = 0; r < 4; ++r)
        Pl[wid][l4 * 4 + r][n * 16 + l15] = f2b(p[n][r]);
#pragma unroll
    for (int kk = 0; kk < 2; ++kk) {
      bf16x8 pa = *(const bf16x8*)&Pl[wid][l15][kk * 32 + l4 * 8];
      const short* vp = Vt + (size_t)(kvh * 128 + l15) * SEQLEN + kt + kk * 32 + l4 * 8;
#pragma unroll
      for (int dt = 0; dt < 8; ++dt) {
        bf16x8 vf = *(const bf16x8*)(vp + (size_t)dt * 16 * SEQLEN);
        o[dt] = __builtin_amdgcn_mfma_f32_16x16x32_bf16(pa, vf, o[dt], 0, 0, 0);
      }
    }
  }

#pragma unroll
  for (int r = 0; r < 4; ++r) {
    float ls = lrow[r];
    ls += __shfl_xor(ls, 1, 64);
    ls += __shfl_xor(ls, 2, 64);
    ls += __shfl_xor(ls, 4, 64);
    ls += __shfl_xor(ls, 8, 64);
    float inv = 1.f / ls;
    int qg = q0 + l4 * 4 + r;
#pragma unroll
    for (int dt = 0; dt < 8; ++dt)
      O[(size_t)qg * 4096 + h * 128 + dt * 16 + l15] = f2b(o[dt][r] * inv);
  }
}

// ---------------------------------------------------------------------------
extern "C" void kernel_launch(void* const* d_in, const int* in_sizes, int n_in,
                              void* d_out, int out_size, void* d_ws, size_t ws_size,
                              hipStream_t stream) {
  const float* x  = (const float*)d_in[0];   // [2048][4096]
  const float* wq = (const float*)d_in[1];   // [4096][4096]
  const float* wk = (const float*)d_in[2];   // [1024][4096]
  const float* wv = (const float*)d_in[3];   // [1024][4096]
  const float* wo = (const float*)d_in[4];   // [4096][4096]
  const float* fc = (const float*)d_in[5];   // [2048][64]
  const float* fs = (const float*)d_in[6];   // [2048][64]

  float* out = (float*)d_out;
  float* out_main = out;                               // [2048][4096] (Q scratch, then final)
  float* cache_k  = out + (size_t)2048 * 4096;         // [4096][8][128]
  float* cache_v  = cache_k + (size_t)4096 * 8 * 128;  // [4096][8][128]

  short* attn_out = (short*)d_ws;                      // bf16 [2048][4096]  16.8 MB
  short* Vt       = attn_out + (size_t)2048 * 4096;    // bf16 [8][128][2048] 4.2 MB

  // 1) projections: Q -> out_main (scratch until final GEMM),
  //    K -> cache_k rows 0..2047, V -> cache_v rows 0..2047
  gemm_bt<false><<<dim3(32, 16), 256, 0, stream>>>(x, wq, out_main, 4096, 4096);
  gemm_bt<false><<<dim3(8, 16),  256, 0, stream>>>(x, wk, cache_k,  4096, 1024);
  gemm_bt<false><<<dim3(8, 16),  256, 0, stream>>>(x, wv, cache_v,  4096, 1024);

  // 2) RoPE (in place, f32) + V transpose (f32 -> bf16); zero cache rows 2048..4095
  rope_f32<<<4096, 256, 0, stream>>>(out_main, fc, fs, 12);
  rope_f32<<<1024, 256, 0, stream>>>(cache_k, fc, fs, 10);
  transpose_v<<<dim3(32, 2, 8), 256, 0, stream>>>(cache_v, Vt);
  hipMemsetAsync(cache_k + (size_t)2048 * 1024, 0, (size_t)2048 * 1024 * 4, stream);
  hipMemsetAsync(cache_v + (size_t)2048 * 1024, 0, (size_t)2048 * 1024 * 4, stream);

  // 3) causal flash attention (bf16 MFMA, f32 softmax) -> bf16 attn_out
  attn_fwd<<<dim3(32, 32), 256, 0, stream>>>(out_main, cache_k, Vt, attn_out);

  // 4) output projection (bf16 A from ws, f32 W) -> final f32 output
  gemm_bt<true><<<dim3(32, 16), 256, 0, stream>>>(attn_out, wo, out_main, 4096, 4096);
}

// Round 5
// 672.287 us; speedup vs baseline: 2.4163x; 2.4163x over previous
//
#include <hip/hip_runtime.h>
#include <hip/hip_bf16.h>

// Device buffers are FLOAT32 (confirmed R4). Compute path: bf16 MFMA, f32 accum.
// Fast path (needs ~54.6 MB ws): pre-convert operands to bf16, m97-style GEMM
// with global_load_lds. Fallback (21 MB ws): R4's f32-staged GEMM (proven).

typedef __attribute__((ext_vector_type(8))) short short8_t;
typedef __attribute__((ext_vector_type(8))) __bf16 bf16x8;
typedef __attribute__((ext_vector_type(4))) float f32x4;

#define SEQLEN 2048
#define ATT_SCALE 0.08838834764831845f

__device__ __forceinline__ short f2b(float f) {
  if (!__builtin_isfinite(f)) f = 0.0f;   // diagnostic scrub (no-op when correct)
  union { float f; unsigned u; } v; v.f = f;
  unsigned r = (v.u + 0x7fffu + ((v.u >> 16) & 1u)) >> 16;  // RNE
  return (short)r;
}
__device__ __forceinline__ float sf(float f) {
  return __builtin_isfinite(f) ? f : 0.0f;
}
__device__ __forceinline__ short8_t cvt8(const float* p) {
  f32x4 a = *(const f32x4*)p;
  f32x4 b = *(const f32x4*)(p + 4);
  short8_t o;
  o[0] = f2b(a[0]); o[1] = f2b(a[1]); o[2] = f2b(a[2]); o[3] = f2b(a[3]);
  o[4] = f2b(b[0]); o[5] = f2b(b[1]); o[6] = f2b(b[2]); o[7] = f2b(b[3]);
  return o;
}

#define GLD16(gp, lp) __builtin_amdgcn_global_load_lds( \
    (const __attribute__((address_space(1))) void*)(gp), \
    (__attribute__((address_space(3))) void*)(lp), 16, 0, 0)

// ---------------------------------------------------------------------------
// f32 -> bf16 elementwise convert (8 elems/thread, exact grid)
// ---------------------------------------------------------------------------
__global__ __launch_bounds__(256) void cvt_bf16(
    const float* __restrict__ in, short* __restrict__ out)
{
  size_t i = ((size_t)blockIdx.x * 256 + threadIdx.x) * 8;
  *(short8_t*)&out[i] = cvt8(in + i);
}

// ---------------------------------------------------------------------------
// FAST GEMM: C[m][n] = sum_k A[m][k]*W[n][k], A/W bf16 row-major, C f32.
// 128x128 tile, BK=64, global_load_lds width16 (m97), 4 waves.
// Split-C: block cols n0 >= splitN go to C2 (col index stays global).
// ---------------------------------------------------------------------------
__global__ __launch_bounds__(256) void gemm_bf(
    const short* __restrict__ A, const short* __restrict__ W,
    float* __restrict__ C1, float* __restrict__ C2,
    int K, int ldc, int splitN)
{
  __shared__ short As[128 * 64];
  __shared__ short Ws[128 * 64];
  const int tid  = threadIdx.x;
  const int lane = tid & 63;
  const int wid  = tid >> 6;
  const int l15  = lane & 15;
  const int l4   = lane >> 4;
  const int m0 = blockIdx.y * 128;
  const int n0 = blockIdx.x * 128;
  const int wr = (wid >> 1) * 64;
  const int wc = (wid & 1) * 64;
  const int srow = tid >> 3;        // 0..31
  const int scol = (tid & 7) * 8;

  f32x4 acc[4][4] = {};

  const short* Ab = A + (size_t)(m0 + srow) * K + scol;
  const short* Wb = W + (size_t)(n0 + srow) * K + scol;

  for (int k0 = 0; k0 < K; k0 += 64) {
#pragma unroll
    for (int i = 0; i < 4; ++i) {
      GLD16(Ab + (size_t)(i * 32) * K + k0, &As[(i * 32 + wid * 8) * 64]);
      GLD16(Wb + (size_t)(i * 32) * K + k0, &Ws[(i * 32 + wid * 8) * 64]);
    }
    __syncthreads();

#pragma unroll
    for (int kk = 0; kk < 2; ++kk) {
      bf16x8 af[4], wf[4];
#pragma unroll
      for (int m = 0; m < 4; ++m)
        af[m] = *(const bf16x8*)&As[(wr + m * 16 + l15) * 64 + kk * 32 + l4 * 8];
#pragma unroll
      for (int n = 0; n < 4; ++n)
        wf[n] = *(const bf16x8*)&Ws[(wc + n * 16 + l15) * 64 + kk * 32 + l4 * 8];
#pragma unroll
      for (int m = 0; m < 4; ++m)
#pragma unroll
        for (int n = 0; n < 4; ++n)
          acc[m][n] = __builtin_amdgcn_mfma_f32_16x16x32_bf16(af[m], wf[n], acc[m][n], 0, 0, 0);
    }
    __syncthreads();
  }

  float* Cb = (n0 < splitN) ? C1 : (C2 - splitN);
#pragma unroll
  for (int m = 0; m < 4; ++m) {
    int rbase = m0 + wr + m * 16 + l4 * 4;
#pragma unroll
    for (int n = 0; n < 4; ++n) {
      int cbase = n0 + wc + n * 16 + l15;
#pragma unroll
      for (int r = 0; r < 4; ++r)
        Cb[(size_t)(rbase + r) * ldc + cbase] = sf(acc[m][n][r]);
    }
  }
}

// ---------------------------------------------------------------------------
// FALLBACK GEMM (R4, proven): W f32 converted in staging.
// ---------------------------------------------------------------------------
template <bool A_BF16>
__global__ __launch_bounds__(256) void gemm_f32w(
    const void* __restrict__ Av, const float* __restrict__ W,
    float* __restrict__ C, int K, int ldc)
{
  __shared__ short As[128 * 64];
  __shared__ short Ws[128 * 64];
  const int tid  = threadIdx.x;
  const int lane = tid & 63;
  const int wid  = tid >> 6;
  const int l15  = lane & 15;
  const int l4   = lane >> 4;
  const int m0 = blockIdx.y * 128;
  const int n0 = blockIdx.x * 128;
  const int wr = (wid >> 1) * 64;
  const int wc = (wid & 1) * 64;
  const int srow = tid >> 3;
  const int scol = (tid & 7) * 8;

  f32x4 acc[4][4] = {};

  for (int k0 = 0; k0 < K; k0 += 64) {
    short8_t va[4], vw[4];
#pragma unroll
    for (int i = 0; i < 4; ++i) {
      int arow = m0 + i * 32 + srow;
      if (A_BF16)
        va[i] = *(const short8_t*)((const short*)Av + (size_t)arow * K + k0 + scol);
      else
        va[i] = cvt8((const float*)Av + (size_t)arow * K + k0 + scol);
      vw[i] = cvt8(W + (size_t)(n0 + i * 32 + srow) * K + k0 + scol);
    }
#pragma unroll
    for (int i = 0; i < 4; ++i) {
      *(short8_t*)&As[(i * 32 + srow) * 64 + scol] = va[i];
      *(short8_t*)&Ws[(i * 32 + srow) * 64 + scol] = vw[i];
    }
    __syncthreads();

#pragma unroll
    for (int kk = 0; kk < 2; ++kk) {
      bf16x8 af[4], wf[4];
#pragma unroll
      for (int m = 0; m < 4; ++m)
        af[m] = *(const bf16x8*)&As[(wr + m * 16 + l15) * 64 + kk * 32 + l4 * 8];
#pragma unroll
      for (int n = 0; n < 4; ++n)
        wf[n] = *(const bf16x8*)&Ws[(wc + n * 16 + l15) * 64 + kk * 32 + l4 * 8];
#pragma unroll
      for (int m = 0; m < 4; ++m)
#pragma unroll
        for (int n = 0; n < 4; ++n)
          acc[m][n] = __builtin_amdgcn_mfma_f32_16x16x32_bf16(af[m], wf[n], acc[m][n], 0, 0, 0);
    }
    __syncthreads();
  }

#pragma unroll
  for (int m = 0; m < 4; ++m) {
    int rbase = m0 + wr + m * 16 + l4 * 4;
#pragma unroll
    for (int n = 0; n < 4; ++n) {
      int cbase = n0 + wc + n * 16 + l15;
#pragma unroll
      for (int r = 0; r < 4; ++r)
        C[(size_t)(rbase + r) * ldc + cbase] = sf(acc[m][n][r]);
    }
  }
}

// ---------------------------------------------------------------------------
// RoPE kernels
// ---------------------------------------------------------------------------
__device__ __forceinline__ void rope8(const float* in, float* out,
                                      const float* fc, const float* fs, int t, int p0)
{
  f32x4 a = *(const f32x4*)in;
  f32x4 b = *(const f32x4*)(in + 4);
  f32x4 cv = *(const f32x4*)&fc[t * 64 + p0];
  f32x4 sv = *(const f32x4*)&fs[t * 64 + p0];
  float x0[8] = {a[0], a[1], a[2], a[3], b[0], b[1], b[2], b[3]};
#pragma unroll
  for (int i = 0; i < 4; ++i) {
    float xr = x0[2 * i], xi = x0[2 * i + 1];
    out[2 * i]     = sf(xr * cv[i] - xi * sv[i]);
    out[2 * i + 1] = sf(xr * sv[i] + xi * cv[i]);
  }
}

// in-place f32 (fallback): logw = log2(row width)
__global__ __launch_bounds__(256) void rope_inplace(
    float* __restrict__ q, const float* __restrict__ fc, const float* __restrict__ fs,
    int logw)
{
  size_t idx = ((size_t)blockIdx.x * 256 + threadIdx.x) * 8;
  int t   = (int)(idx >> logw);
  int col = (int)(idx & ((1 << logw) - 1));
  float o[8];
  rope8(&q[idx], o, fc, fs, t, (col & 127) >> 1);
  *(f32x4*)&q[idx]     = f32x4{o[0], o[1], o[2], o[3]};
  *(f32x4*)&q[idx + 4] = f32x4{o[4], o[5], o[6], o[7]};
}

// fast: Q f32 [2048][4096] -> bf16 q_bf
__global__ __launch_bounds__(256) void rope_q_bf(
    const float* __restrict__ q, short* __restrict__ qb,
    const float* __restrict__ fc, const float* __restrict__ fs)
{
  size_t idx = ((size_t)blockIdx.x * 256 + threadIdx.x) * 8;
  int t   = (int)(idx >> 12);
  int col = (int)(idx & 4095);
  float o[8];
  rope8(&q[idx], o, fc, fs, t, (col & 127) >> 1);
  short8_t ob;
#pragma unroll
  for (int i = 0; i < 8; ++i) ob[i] = f2b(o[i]);
  *(short8_t*)&qb[idx] = ob;
}

// fast: cache_k f32 in-place + bf16 copy
__global__ __launch_bounds__(256) void rope_k_dual(
    float* __restrict__ ck, short* __restrict__ kb,
    const float* __restrict__ fc, const float* __restrict__ fs)
{
  size_t idx = ((size_t)blockIdx.x * 256 + threadIdx.x) * 8;
  int t   = (int)(idx >> 10);
  int col = (int)(idx & 1023);
  float o[8];
  rope8(&ck[idx], o, fc, fs, t, (col & 127) >> 1);
  *(f32x4*)&ck[idx]     = f32x4{o[0], o[1], o[2], o[3]};
  *(f32x4*)&ck[idx + 4] = f32x4{o[4], o[5], o[6], o[7]};
  short8_t ob;
#pragma unroll
  for (int i = 0; i < 8; ++i) ob[i] = f2b(o[i]);
  *(short8_t*)&kb[idx] = ob;
}

// cache_v f32 [2048][8*128] -> Vt bf16 [8][128][2048]
__global__ __launch_bounds__(256) void transpose_v(
    const float* __restrict__ cv, short* __restrict__ Vt)
{
  __shared__ short tile[64][72];
  const int t0 = blockIdx.x * 64;
  const int d0 = blockIdx.y * 64;
  const int h  = blockIdx.z;
  const int tid = threadIdx.x;
  const int r = tid >> 3;
  const int c = (tid & 7) * 8;
#pragma unroll
  for (int it = 0; it < 2; ++it) {
    short8_t v = cvt8(&cv[(size_t)(t0 + it * 32 + r) * 1024 + h * 128 + d0 + c]);
    *(short8_t*)&tile[it * 32 + r][c] = v;
  }
  __syncthreads();
#pragma unroll
  for (int it = 0; it < 2; ++it) {
    int dr = it * 32 + r;
    short8_t v;
#pragma unroll
    for (int i = 0; i < 8; ++i) v[i] = tile[c + i][dr];
    *(short8_t*)&Vt[(size_t)(h * 128 + d0 + dr) * SEQLEN + t0 + c] = v;
  }
}

// ---------------------------------------------------------------------------
// Causal flash attention. Grid (16, 32): block does q-tiles {x, 31-x} (balanced
// 33 KV-iters each). 4 waves/block, 16 q-rows/wave, KV tiles of 64.
// QKBF: Q [2048][4096], K [2048][1024] are bf16 (fast) or f32 (fallback).
// Defer-max (THR=8) skips O-rescale when tile max doesn't grow.
// ---------------------------------------------------------------------------
template <bool QKBF>
__global__ __launch_bounds__(256) void attn_fwd(
    const void* __restrict__ Qv, const void* __restrict__ Kv,
    const short* __restrict__ Vt, short* __restrict__ O)
{
  const int h   = blockIdx.y;
  const int kvh = h >> 2;
  const int tid = threadIdx.x;
  const int wid = tid >> 6;
  const int lane = tid & 63;
  const int l15 = lane & 15;
  const int l4  = lane >> 4;

  __shared__ short Pl[4][16][72];

  for (int half = 0; half < 2; ++half) {
    const int qt = half ? (31 - (int)blockIdx.x) : (int)blockIdx.x;
    const int q0 = qt * 64 + wid * 16;

    bf16x8 qf[4];
    if (QKBF) {
      const short* qp = (const short*)Qv + (size_t)(q0 + l15) * 4096 + h * 128 + l4 * 8;
#pragma unroll
      for (int kc = 0; kc < 4; ++kc) qf[kc] = *(const bf16x8*)(qp + kc * 32);
    } else {
      const float* qp = (const float*)Qv + (size_t)(q0 + l15) * 4096 + h * 128 + l4 * 8;
#pragma unroll
      for (int kc = 0; kc < 4; ++kc) {
        short8_t v = cvt8(qp + kc * 32);
        qf[kc] = *(const bf16x8*)&v;
      }
    }

    f32x4 o[8] = {};
    float mrow[4] = {-1e30f, -1e30f, -1e30f, -1e30f};
    float lrow[4] = {0.f, 0.f, 0.f, 0.f};

    const int kend = q0 + 16;
    for (int kt = 0; kt < kend; kt += 64) {
      f32x4 s[4] = {};
#pragma unroll
      for (int n = 0; n < 4; ++n) {
        if (QKBF) {
          const short* kp = (const short*)Kv + (size_t)(kt + n * 16 + l15) * 1024 + kvh * 128 + l4 * 8;
#pragma unroll
          for (int kc = 0; kc < 4; ++kc) {
            bf16x8 kf = *(const bf16x8*)(kp + kc * 32);
            s[n] = __builtin_amdgcn_mfma_f32_16x16x32_bf16(qf[kc], kf, s[n], 0, 0, 0);
          }
        } else {
          const float* kp = (const float*)Kv + (size_t)(kt + n * 16 + l15) * 1024 + kvh * 128 + l4 * 8;
#pragma unroll
          for (int kc = 0; kc < 4; ++kc) {
            short8_t kv = cvt8(kp + kc * 32);
            s[n] = __builtin_amdgcn_mfma_f32_16x16x32_bf16(qf[kc], *(const bf16x8*)&kv, s[n], 0, 0, 0);
          }
        }
      }

      // scale + mask + per-row max
      float p[4][4], mx[4];
      int okall = 1;
#pragma unroll
      for (int r = 0; r < 4; ++r) {
        int qg = q0 + l4 * 4 + r;
        float m = -1e30f;
#pragma unroll
        for (int n = 0; n < 4; ++n) {
          int kg = kt + n * 16 + l15;
          float val = (kg <= qg) ? s[n][r] * ATT_SCALE : -1e9f;
          p[n][r] = val;
          m = fmaxf(m, val);
        }
        m = fmaxf(m, __shfl_xor(m, 1, 64));
        m = fmaxf(m, __shfl_xor(m, 2, 64));
        m = fmaxf(m, __shfl_xor(m, 4, 64));
        m = fmaxf(m, __shfl_xor(m, 8, 64));
        mx[r] = m;
        okall &= (m <= mrow[r] + 8.f);
      }

      if (__all(okall)) {
        // defer-max: keep old max, no O-rescale (p bounded by e^8)
#pragma unroll
        for (int r = 0; r < 4; ++r) {
          float psum = 0.f;
#pragma unroll
          for (int n = 0; n < 4; ++n) {
            float e = __expf(p[n][r] - mrow[r]);
            p[n][r] = e;
            psum += e;
          }
          lrow[r] += psum;
        }
      } else {
#pragma unroll
        for (int r = 0; r < 4; ++r) {
          float mnew = fmaxf(mrow[r], mx[r]);
          float resc = __expf(mrow[r] - mnew);
          mrow[r] = mnew;
          float psum = 0.f;
#pragma unroll
          for (int n = 0; n < 4; ++n) {
            float e = __expf(p[n][r] - mnew);
            p[n][r] = e;
            psum += e;
          }
          lrow[r] = lrow[r] * resc + psum;
#pragma unroll
          for (int dt = 0; dt < 8; ++dt) o[dt][r] *= resc;
        }
      }

#pragma unroll
      for (int n = 0; n < 4; ++n)
#pragma unroll
        for (int r = 0; r < 4; ++r)
          Pl[wid][l4 * 4 + r][n * 16 + l15] = f2b(p[n][r]);
#pragma unroll
      for (int kk = 0; kk < 2; ++kk) {
        bf16x8 pa = *(const bf16x8*)&Pl[wid][l15][kk * 32 + l4 * 8];
        const short* vp = Vt + (size_t)(kvh * 128 + l15) * SEQLEN + kt + kk * 32 + l4 * 8;
#pragma unroll
        for (int dt = 0; dt < 8; ++dt) {
          bf16x8 vf = *(const bf16x8*)(vp + (size_t)dt * 16 * SEQLEN);
          o[dt] = __builtin_amdgcn_mfma_f32_16x16x32_bf16(pa, vf, o[dt], 0, 0, 0);
        }
      }
    }

#pragma unroll
    for (int r = 0; r < 4; ++r) {
      float ls = lrow[r];
      ls += __shfl_xor(ls, 1, 64);
      ls += __shfl_xor(ls, 2, 64);
      ls += __shfl_xor(ls, 4, 64);
      ls += __shfl_xor(ls, 8, 64);
      float inv = 1.f / ls;
      int qg = q0 + l4 * 4 + r;
#pragma unroll
      for (int dt = 0; dt < 8; ++dt)
        O[(size_t)qg * 4096 + h * 128 + dt * 16 + l15] = f2b(o[dt][r] * inv);
    }
  }
}

// ---------------------------------------------------------------------------
extern "C" void kernel_launch(void* const* d_in, const int* in_sizes, int n_in,
                              void* d_out, int out_size, void* d_ws, size_t ws_size,
                              hipStream_t stream) {
  const float* x  = (const float*)d_in[0];   // [2048][4096]
  const float* wq = (const float*)d_in[1];   // [4096][4096]
  const float* wk = (const float*)d_in[2];   // [1024][4096]
  const float* wv = (const float*)d_in[3];   // [1024][4096]
  const float* wo = (const float*)d_in[4];   // [4096][4096]
  const float* fc = (const float*)d_in[5];   // [2048][64]
  const float* fs = (const float*)d_in[6];   // [2048][64]

  float* out = (float*)d_out;
  float* out_main = out;                               // [2048][4096]
  float* cache_k  = out + (size_t)2048 * 4096;         // [4096][8][128]
  float* cache_v  = cache_k + (size_t)4096 * 8 * 128;  // [4096][8][128]

  const size_t MB_W  = 33554432;   // 4096x4096 bf16
  const size_t MB_X  = 16777216;   // 2048x4096 bf16
  const size_t MB_V  = 4194304;    // 8x128x2048 bf16
  const size_t FAST_NEED = MB_W + MB_X + MB_V;  // 54,525,952

  if (ws_size >= FAST_NEED) {
    // ws layout (time-multiplexed):
    // slotA [0, 33.5MB): w_bf (wq | wk+wv | wo)  /  q_bf + k_bf during attn
    // slotB [33.5, 50.3MB): x_bf  /  attn_out
    // slotC [50.3, 54.5MB): Vt
    short* slotA = (short*)d_ws;
    short* x_bf  = (short*)((char*)d_ws + MB_W);
    short* attn_out = x_bf;                 // reuses slotB after x_bf dead
    short* Vt    = (short*)((char*)d_ws + MB_W + MB_X);
    short* q_bf  = slotA;
    short* k_bf  = slotA + (size_t)2048 * 4096;

    // converts + projections
    cvt_bf16<<<4096, 256, 0, stream>>>(x, x_bf);
    cvt_bf16<<<8192, 256, 0, stream>>>(wq, slotA);
    gemm_bf<<<dim3(32, 16), 256, 0, stream>>>(x_bf, slotA, out_main, out_main, 4096, 4096, 1 << 30);
    cvt_bf16<<<2048, 256, 0, stream>>>(wk, slotA);
    cvt_bf16<<<2048, 256, 0, stream>>>(wv, slotA + (size_t)1024 * 4096);
    gemm_bf<<<dim3(16, 16), 256, 0, stream>>>(x_bf, slotA, cache_k, cache_v, 4096, 1024, 1024);

    // RoPE (Q f32->bf16, K in-place + bf16) + V transpose + cache tail zeros
    rope_q_bf<<<4096, 256, 0, stream>>>(out_main, q_bf, fc, fs);
    rope_k_dual<<<1024, 256, 0, stream>>>(cache_k, k_bf, fc, fs);
    transpose_v<<<dim3(32, 2, 8), 256, 0, stream>>>(cache_v, Vt);
    hipMemsetAsync(cache_k + (size_t)2048 * 1024, 0, (size_t)2048 * 1024 * 4, stream);
    hipMemsetAsync(cache_v + (size_t)2048 * 1024, 0, (size_t)2048 * 1024 * 4, stream);

    // attention (bf16 Q/K)
    attn_fwd<true><<<dim3(16, 32), 256, 0, stream>>>(q_bf, k_bf, Vt, attn_out);

    // output projection
    cvt_bf16<<<8192, 256, 0, stream>>>(wo, slotA);
    gemm_bf<<<dim3(32, 16), 256, 0, stream>>>(attn_out, slotA, out_main, out_main, 4096, 4096, 1 << 30);
  } else {
    // fallback: R4-proven f32-staged path (21 MB ws)
    short* attn_out = (short*)d_ws;
    short* Vt       = attn_out + (size_t)2048 * 4096;

    gemm_f32w<false><<<dim3(32, 16), 256, 0, stream>>>(x, wq, out_main, 4096, 4096);
    gemm_f32w<false><<<dim3(8, 16),  256, 0, stream>>>(x, wk, cache_k,  4096, 1024);
    gemm_f32w<false><<<dim3(8, 16),  256, 0, stream>>>(x, wv, cache_v,  4096, 1024);

    rope_inplace<<<4096, 256, 0, stream>>>(out_main, fc, fs, 12);
    rope_inplace<<<1024, 256, 0, stream>>>(cache_k, fc, fs, 10);
    transpose_v<<<dim3(32, 2, 8), 256, 0, stream>>>(cache_v, Vt);
    hipMemsetAsync(cache_k + (size_t)2048 * 1024, 0, (size_t)2048 * 1024 * 4, stream);
    hipMemsetAsync(cache_v + (size_t)2048 * 1024, 0, (size_t)2048 * 1024 * 4, stream);

    attn_fwd<false><<<dim3(16, 32), 256, 0, stream>>>(out_main, cache_k, Vt, attn_out);

    gemm_f32w<true><<<dim3(32, 16), 256, 0, stream>>>(attn_out, wo, out_main, 4096, 4096);
  }
}

// Round 7
// 555.155 us; speedup vs baseline: 2.9261x; 1.2110x over previous
//
#include <hip/hip_runtime.h>
#include <hip/hip_bf16.h>

// Device buffers are FLOAT32 (confirmed R4/R5). bf16 MFMA compute, f32 accum.
// R6->R7: attention keeps swapped-QK^T 32x32 + in-lane softmax + defer-max,
// but replaces ALL inline asm (cvt_pk/permlane pfrag, xhalf) with LDS-staged
// P transpose + __shfl_xor(32) — bisecting R6's finite-wrong failure.

typedef __attribute__((ext_vector_type(8))) short short8_t;
typedef __attribute__((ext_vector_type(8))) __bf16 bf16x8;
typedef __attribute__((ext_vector_type(4))) float f32x4;
typedef __attribute__((ext_vector_type(16))) float f32x16;

#define SEQLEN 2048
#define QSCALE 0.08838834764831845f   // HEAD_DIM^-0.5, folded into Q at RoPE

__device__ __forceinline__ short f2b(float f) {
  if (!__builtin_isfinite(f)) f = 0.0f;   // diagnostic scrub (no-op when correct)
  union { float f; unsigned u; } v; v.f = f;
  unsigned r = (v.u + 0x7fffu + ((v.u >> 16) & 1u)) >> 16;  // RNE
  return (short)r;
}
__device__ __forceinline__ float sf(float f) {
  return __builtin_isfinite(f) ? f : 0.0f;
}
__device__ __forceinline__ short8_t cvt8(const float* p) {
  f32x4 a = *(const f32x4*)p;
  f32x4 b = *(const f32x4*)(p + 4);
  short8_t o;
  o[0] = f2b(a[0]); o[1] = f2b(a[1]); o[2] = f2b(a[2]); o[3] = f2b(a[3]);
  o[4] = f2b(b[0]); o[5] = f2b(b[1]); o[6] = f2b(b[2]); o[7] = f2b(b[3]);
  return o;
}
// pack two f32 -> (bf16 hi<<16 | bf16 lo)
__device__ __forceinline__ unsigned pkb(float lo, float hi) {
  return ((unsigned)(unsigned short)f2b(hi) << 16) | (unsigned short)f2b(lo);
}

#define GLD16(gp, lp) __builtin_amdgcn_global_load_lds( \
    (const __attribute__((address_space(1))) void*)(gp), \
    (__attribute__((address_space(3))) void*)(lp), 16, 0, 0)

// ---------------------------------------------------------------------------
__global__ __launch_bounds__(256) void cvt_bf16(
    const float* __restrict__ in, short* __restrict__ out)
{
  size_t i = ((size_t)blockIdx.x * 256 + threadIdx.x) * 8;
  *(short8_t*)&out[i] = cvt8(in + i);
}

// ---------------------------------------------------------------------------
// GEMM: C[m][n] = sum_k A[m][k]*W[n][k], A/W bf16, C f32. m97 structure.
// ---------------------------------------------------------------------------
__global__ __launch_bounds__(256) void gemm_bf(
    const short* __restrict__ A, const short* __restrict__ W,
    float* __restrict__ C1, float* __restrict__ C2,
    int K, int ldc, int splitN)
{
  __shared__ short As[128 * 64];
  __shared__ short Ws[128 * 64];
  const int tid  = threadIdx.x;
  const int lane = tid & 63;
  const int wid  = tid >> 6;
  const int l15  = lane & 15;
  const int l4   = lane >> 4;
  const int m0 = blockIdx.y * 128;
  const int n0 = blockIdx.x * 128;
  const int wr = (wid >> 1) * 64;
  const int wc = (wid & 1) * 64;
  const int srow = tid >> 3;
  const int scol = (tid & 7) * 8;

  f32x4 acc[4][4] = {};

  const short* Ab = A + (size_t)(m0 + srow) * K + scol;
  const short* Wb = W + (size_t)(n0 + srow) * K + scol;

  for (int k0 = 0; k0 < K; k0 += 64) {
#pragma unroll
    for (int i = 0; i < 4; ++i) {
      GLD16(Ab + (size_t)(i * 32) * K + k0, &As[(i * 32 + wid * 8) * 64]);
      GLD16(Wb + (size_t)(i * 32) * K + k0, &Ws[(i * 32 + wid * 8) * 64]);
    }
    __syncthreads();

#pragma unroll
    for (int kk = 0; kk < 2; ++kk) {
      bf16x8 af[4], wf[4];
#pragma unroll
      for (int m = 0; m < 4; ++m)
        af[m] = *(const bf16x8*)&As[(wr + m * 16 + l15) * 64 + kk * 32 + l4 * 8];
#pragma unroll
      for (int n = 0; n < 4; ++n)
        wf[n] = *(const bf16x8*)&Ws[(wc + n * 16 + l15) * 64 + kk * 32 + l4 * 8];
#pragma unroll
      for (int m = 0; m < 4; ++m)
#pragma unroll
        for (int n = 0; n < 4; ++n)
          acc[m][n] = __builtin_amdgcn_mfma_f32_16x16x32_bf16(af[m], wf[n], acc[m][n], 0, 0, 0);
    }
    __syncthreads();
  }

  float* Cb = (n0 < splitN) ? C1 : (C2 - splitN);
#pragma unroll
  for (int m = 0; m < 4; ++m) {
    int rbase = m0 + wr + m * 16 + l4 * 4;
#pragma unroll
    for (int n = 0; n < 4; ++n) {
      int cbase = n0 + wc + n * 16 + l15;
#pragma unroll
      for (int r = 0; r < 4; ++r)
        Cb[(size_t)(rbase + r) * ldc + cbase] = sf(acc[m][n][r]);
    }
  }
}

// ---------------------------------------------------------------------------
// RoPE
// ---------------------------------------------------------------------------
__device__ __forceinline__ void rope8(const float* in, float* out,
                                      const float* fc, const float* fs, int t, int p0)
{
  f32x4 a = *(const f32x4*)in;
  f32x4 b = *(const f32x4*)(in + 4);
  f32x4 cv = *(const f32x4*)&fc[t * 64 + p0];
  f32x4 sv = *(const f32x4*)&fs[t * 64 + p0];
  float x0[8] = {a[0], a[1], a[2], a[3], b[0], b[1], b[2], b[3]};
#pragma unroll
  for (int i = 0; i < 4; ++i) {
    float xr = x0[2 * i], xi = x0[2 * i + 1];
    out[2 * i]     = sf(xr * cv[i] - xi * sv[i]);
    out[2 * i + 1] = sf(xr * sv[i] + xi * cv[i]);
  }
}

// Q: f32 [2048][4096] -> bf16 q_bf, pre-scaled by QSCALE
__global__ __launch_bounds__(256) void rope_q_bf(
    const float* __restrict__ q, short* __restrict__ qb,
    const float* __restrict__ fc, const float* __restrict__ fs)
{
  size_t idx = ((size_t)blockIdx.x * 256 + threadIdx.x) * 8;
  int t   = (int)(idx >> 12);
  int col = (int)(idx & 4095);
  float o[8];
  rope8(&q[idx], o, fc, fs, t, (col & 127) >> 1);
  short8_t ob;
#pragma unroll
  for (int i = 0; i < 8; ++i) ob[i] = f2b(o[i] * QSCALE);
  *(short8_t*)&qb[idx] = ob;
}

// K: cache_k f32 in-place + bf16 copy (unscaled)
__global__ __launch_bounds__(256) void rope_k_dual(
    float* __restrict__ ck, short* __restrict__ kb,
    const float* __restrict__ fc, const float* __restrict__ fs)
{
  size_t idx = ((size_t)blockIdx.x * 256 + threadIdx.x) * 8;
  int t   = (int)(idx >> 10);
  int col = (int)(idx & 1023);
  float o[8];
  rope8(&ck[idx], o, fc, fs, t, (col & 127) >> 1);
  *(f32x4*)&ck[idx]     = f32x4{o[0], o[1], o[2], o[3]};
  *(f32x4*)&ck[idx + 4] = f32x4{o[4], o[5], o[6], o[7]};
  short8_t ob;
#pragma unroll
  for (int i = 0; i < 8; ++i) ob[i] = f2b(o[i]);
  *(short8_t*)&kb[idx] = ob;
}

// cache_v f32 [2048][8*128] -> Vt bf16 [8][128][2048]
__global__ __launch_bounds__(256) void transpose_v(
    const float* __restrict__ cv, short* __restrict__ Vt)
{
  __shared__ short tile[64][72];
  const int t0 = blockIdx.x * 64;
  const int d0 = blockIdx.y * 64;
  const int h  = blockIdx.z;
  const int tid = threadIdx.x;
  const int r = tid >> 3;
  const int c = (tid & 7) * 8;
#pragma unroll
  for (int it = 0; it < 2; ++it) {
    short8_t v = cvt8(&cv[(size_t)(t0 + it * 32 + r) * 1024 + h * 128 + d0 + c]);
    *(short8_t*)&tile[it * 32 + r][c] = v;
  }
  __syncthreads();
#pragma unroll
  for (int it = 0; it < 2; ++it) {
    int dr = it * 32 + r;
    short8_t v;
#pragma unroll
    for (int i = 0; i < 8; ++i) v[i] = tile[c + i][dr];
    *(short8_t*)&Vt[(size_t)(h * 128 + d0 + dr) * SEQLEN + t0 + c] = v;
  }
}

// ---------------------------------------------------------------------------
// Causal flash attention, swapped-QK^T 32x32 MFMA.
// Grid (16, 32), 4 waves/block. Waves 0,1 -> qtile x; waves 2,3 -> qtile 31-x.
// Lane state: q = lane&31, S^T keys = crow(r,hi) = (r&3)+8*(r>>2)+4*hi.
// P staged per-wave through LDS [q][key] (no inline asm anywhere).
// ---------------------------------------------------------------------------
__global__ __launch_bounds__(256) void attn_fwd2(
    const short* __restrict__ Q,    // [2048][4096] bf16, pre-scaled
    const short* __restrict__ Kc,   // [2048][1024] bf16
    const short* __restrict__ Vt,   // [8][128][2048] bf16
    short* __restrict__ O)          // [2048][4096] bf16
{
  const int h   = blockIdx.y;
  const int kvh = h >> 2;
  const int tid = threadIdx.x;
  const int wid = tid >> 6;
  const int lane = tid & 63;
  const int l31 = lane & 31;
  const int hi  = lane >> 5;

  __shared__ short P_lds[4][32][80];   // per-wave [q][key] bf16 (cols 64..79 pad)
  __shared__ float exch[4][32];

  const int qt = (wid < 2) ? (int)blockIdx.x : (31 - (int)blockIdx.x);
  const int q0 = qt * 64 + (wid & 1) * 32;
  const int qg = q0 + l31;

  // Q B-frags (loop-invariant): k = ks*16 + hi*8
  bf16x8 qf[8];
  {
    const short* qp = Q + (size_t)qg * 4096 + h * 128 + hi * 8;
#pragma unroll
    for (int ks = 0; ks < 8; ++ks) qf[ks] = *(const bf16x8*)(qp + ks * 16);
  }

  f32x16 o0 = {}, o1 = {}, o2 = {}, o3 = {};
  float m = -1e30f, l = 0.f;

  const int kend = q0 + 32;
  for (int kt = 0; kt < kend; kt += 64) {
    // S^T = K * Q^T (two 32-key tiles)
    f32x16 s0 = {}, s1 = {};
    {
      const short* kp = Kc + (size_t)(kt + l31) * 1024 + kvh * 128 + hi * 8;
#pragma unroll
      for (int ks = 0; ks < 8; ++ks) {
        bf16x8 k0 = *(const bf16x8*)(kp + ks * 16);
        bf16x8 k1 = *(const bf16x8*)(kp + 32 * 1024 + ks * 16);
        s0 = __builtin_amdgcn_mfma_f32_32x32x16_bf16(k0, qf[ks], s0, 0, 0, 0);
        s1 = __builtin_amdgcn_mfma_f32_32x32x16_bf16(k1, qf[ks], s1, 0, 0, 0);
      }
    }

    // causal mask (diagonal tile only)
    if (kt + 63 > q0) {
#pragma unroll
      for (int r = 0; r < 16; ++r) {
        int crow = (r & 3) + 8 * (r >> 2) + 4 * hi;
        if (kt + crow > qg)      s0[r] = -1e30f;
        if (kt + 32 + crow > qg) s1[r] = -1e30f;
      }
    }

    // per-q max over 64 keys: in-lane tree + cross-half shuffle
    float t[8];
#pragma unroll
    for (int r = 0; r < 8; ++r)
      t[r] = fmaxf(fmaxf(s0[r], s0[r + 8]), fmaxf(s1[r], s1[r + 8]));
    float pmax = fmaxf(fmaxf(fmaxf(t[0], t[1]), fmaxf(t[2], t[3])),
                       fmaxf(fmaxf(t[4], t[5]), fmaxf(t[6], t[7])));
    pmax = fmaxf(pmax, __shfl_xor(pmax, 32, 64));

    // defer-max (T13): rescale only when tile max grows past m+8
    if (!__all(pmax <= m + 8.f)) {
      float mnew = fmaxf(m, pmax);
      float resc = __expf(m - mnew);
      m = mnew;
      l *= resc;
      if (lane < 32) exch[wid][l31] = resc;
#pragma unroll
      for (int r = 0; r < 16; ++r) {
        float rs = exch[wid][(r & 3) + 8 * (r >> 2) + 4 * hi];
        o0[r] *= rs; o1[r] *= rs; o2[r] *= rs; o3[r] *= rs;
      }
    }

    // p = exp(s - m) in place, row sum
    float psum = 0.f;
#pragma unroll
    for (int r = 0; r < 16; ++r) { s0[r] = __expf(s0[r] - m); psum += s0[r]; }
#pragma unroll
    for (int r = 0; r < 16; ++r) { s1[r] = __expf(s1[r] - m); psum += s1[r]; }
    l += psum + __shfl_xor(psum, 32, 64);

    // P -> LDS [q][key] (pairs r=2t,2t+1 are consecutive keys)
#pragma unroll
    for (int t2 = 0; t2 < 8; ++t2) {
      int c = ((2 * t2) & 3) + 8 * ((2 * t2) >> 2) + 4 * hi;
      *(unsigned*)&P_lds[wid][l31][c]      = pkb(s0[2 * t2], s0[2 * t2 + 1]);
      *(unsigned*)&P_lds[wid][l31][32 + c] = pkb(s1[2 * t2], s1[2 * t2 + 1]);
    }

    // PV: 4 x 16-key subtiles; A-frag = ds_read_b128 from P_lds
    const short* vb = Vt + (size_t)(kvh * 128 + l31) * SEQLEN + kt + hi * 8;
#pragma unroll
    for (int g = 0; g < 4; ++g) {
      bf16x8 pf = *(const bf16x8*)&P_lds[wid][l31][g * 16 + hi * 8];
      const short* vg = vb + g * 16;
      o0 = __builtin_amdgcn_mfma_f32_32x32x16_bf16(pf, *(const bf16x8*)(vg),                       o0, 0, 0, 0);
      o1 = __builtin_amdgcn_mfma_f32_32x32x16_bf16(pf, *(const bf16x8*)(vg + 32 * SEQLEN),         o1, 0, 0, 0);
      o2 = __builtin_amdgcn_mfma_f32_32x32x16_bf16(pf, *(const bf16x8*)(vg + 64 * SEQLEN),         o2, 0, 0, 0);
      o3 = __builtin_amdgcn_mfma_f32_32x32x16_bf16(pf, *(const bf16x8*)(vg + (size_t)96 * SEQLEN), o3, 0, 0, 0);
    }
  }

  // normalize + store: row q = q0+crow(r,hi), col d = dtile*32 + l31
  if (lane < 32) exch[wid][l31] = 1.f / l;
#pragma unroll
  for (int r = 0; r < 16; ++r) {
    int crow = (r & 3) + 8 * (r >> 2) + 4 * hi;
    float inv = exch[wid][crow];
    short* ob = O + (size_t)(q0 + crow) * 4096 + h * 128 + l31;
    ob[0]  = f2b(o0[r] * inv);
    ob[32] = f2b(o1[r] * inv);
    ob[64] = f2b(o2[r] * inv);
    ob[96] = f2b(o3[r] * inv);
  }
}

// ---------------------------------------------------------------------------
extern "C" void kernel_launch(void* const* d_in, const int* in_sizes, int n_in,
                              void* d_out, int out_size, void* d_ws, size_t ws_size,
                              hipStream_t stream) {
  const float* x  = (const float*)d_in[0];
  const float* wq = (const float*)d_in[1];
  const float* wk = (const float*)d_in[2];
  const float* wv = (const float*)d_in[3];
  const float* wo = (const float*)d_in[4];
  const float* fc = (const float*)d_in[5];
  const float* fs = (const float*)d_in[6];

  float* out = (float*)d_out;
  float* out_main = out;                               // [2048][4096]
  float* cache_k  = out + (size_t)2048 * 4096;         // [4096][8][128]
  float* cache_v  = cache_k + (size_t)4096 * 8 * 128;  // [4096][8][128]

  const size_t MB_W = 33554432;   // 4096x4096 bf16
  const size_t MB_X = 16777216;   // 2048x4096 bf16
  // ws (>= 54.6 MB, confirmed R5):
  // slotA [0, 33.5MB): w_bf  /  q_bf + k_bf during attn
  // slotB [33.5, 50.3MB): x_bf  /  attn_out
  // slotC [50.3, 54.5MB): Vt
  short* slotA = (short*)d_ws;
  short* x_bf  = (short*)((char*)d_ws + MB_W);
  short* attn_out = x_bf;
  short* Vt    = (short*)((char*)d_ws + MB_W + MB_X);
  short* q_bf  = slotA;
  short* k_bf  = slotA + (size_t)2048 * 4096;

  // converts + projections
  cvt_bf16<<<4096, 256, 0, stream>>>(x, x_bf);
  cvt_bf16<<<8192, 256, 0, stream>>>(wq, slotA);
  gemm_bf<<<dim3(32, 16), 256, 0, stream>>>(x_bf, slotA, out_main, out_main, 4096, 4096, 1 << 30);
  cvt_bf16<<<2048, 256, 0, stream>>>(wk, slotA);
  cvt_bf16<<<2048, 256, 0, stream>>>(wv, slotA + (size_t)1024 * 4096);
  gemm_bf<<<dim3(16, 16), 256, 0, stream>>>(x_bf, slotA, cache_k, cache_v, 4096, 1024, 1024);

  // RoPE + V transpose + cache tail zeros
  rope_q_bf<<<4096, 256, 0, stream>>>(out_main, q_bf, fc, fs);
  rope_k_dual<<<1024, 256, 0, stream>>>(cache_k, k_bf, fc, fs);
  transpose_v<<<dim3(32, 2, 8), 256, 0, stream>>>(cache_v, Vt);
  hipMemsetAsync(cache_k + (size_t)2048 * 1024, 0, (size_t)2048 * 1024 * 4, stream);
  hipMemsetAsync(cache_v + (size_t)2048 * 1024, 0, (size_t)2048 * 1024 * 4, stream);

  // attention
  attn_fwd2<<<dim3(16, 32), 256, 0, stream>>>(q_bf, k_bf, Vt, attn_out);

  // output projection
  cvt_bf16<<<8192, 256, 0, stream>>>(wo, slotA);
  gemm_bf<<<dim3(32, 16), 256, 0, stream>>>(attn_out, slotA, out_main, out_main, 4096, 4096, 1 << 30);
}

// Round 8
// 532.937 us; speedup vs baseline: 3.0481x; 1.0417x over previous
//
#include <hip/hip_runtime.h>
#include <hip/hip_bf16.h>

// Device buffers are FLOAT32 (confirmed R4/R5). bf16 MFMA compute, f32 accum.
// R7->R8: attention re-gridded to 2048 single-wave blocks, heavy-first order
// (fixes 7.4% occupancy / block imbalance), P_lds pad 88 (4-way vs 8-way),
// b64 P-writes, setprio around MFMA. GEMMs: +XCD-aware block swizzle.

typedef __attribute__((ext_vector_type(8))) short short8_t;
typedef __attribute__((ext_vector_type(2))) unsigned uint2_t;
typedef __attribute__((ext_vector_type(8))) __bf16 bf16x8;
typedef __attribute__((ext_vector_type(4))) float f32x4;
typedef __attribute__((ext_vector_type(16))) float f32x16;

#define SEQLEN 2048
#define QSCALE 0.08838834764831845f   // HEAD_DIM^-0.5, folded into Q at RoPE

__device__ __forceinline__ short f2b(float f) {
  if (!__builtin_isfinite(f)) f = 0.0f;   // diagnostic scrub (no-op when correct)
  union { float f; unsigned u; } v; v.f = f;
  unsigned r = (v.u + 0x7fffu + ((v.u >> 16) & 1u)) >> 16;  // RNE
  return (short)r;
}
__device__ __forceinline__ float sf(float f) {
  return __builtin_isfinite(f) ? f : 0.0f;
}
__device__ __forceinline__ short8_t cvt8(const float* p) {
  f32x4 a = *(const f32x4*)p;
  f32x4 b = *(const f32x4*)(p + 4);
  short8_t o;
  o[0] = f2b(a[0]); o[1] = f2b(a[1]); o[2] = f2b(a[2]); o[3] = f2b(a[3]);
  o[4] = f2b(b[0]); o[5] = f2b(b[1]); o[6] = f2b(b[2]); o[7] = f2b(b[3]);
  return o;
}
// pack two f32 -> (bf16 hi<<16 | bf16 lo)
__device__ __forceinline__ unsigned pkb(float lo, float hi) {
  return ((unsigned)(unsigned short)f2b(hi) << 16) | (unsigned short)f2b(lo);
}

#define GLD16(gp, lp) __builtin_amdgcn_global_load_lds( \
    (const __attribute__((address_space(1))) void*)(gp), \
    (__attribute__((address_space(3))) void*)(lp), 16, 0, 0)

// ---------------------------------------------------------------------------
__global__ __launch_bounds__(256) void cvt_bf16(
    const float* __restrict__ in, short* __restrict__ out)
{
  size_t i = ((size_t)blockIdx.x * 256 + threadIdx.x) * 8;
  *(short8_t*)&out[i] = cvt8(in + i);
}

// ---------------------------------------------------------------------------
// GEMM: C[m][n] = sum_k A[m][k]*W[n][k], A/W bf16, C f32. m97 structure.
// XCD-aware swizzle on flattened block id (grid size divisible by 8).
// ---------------------------------------------------------------------------
__global__ __launch_bounds__(256) void gemm_bf(
    const short* __restrict__ A, const short* __restrict__ W,
    float* __restrict__ C1, float* __restrict__ C2,
    int K, int ldc, int splitN)
{
  __shared__ short As[128 * 64];
  __shared__ short Ws[128 * 64];
  const int tid  = threadIdx.x;
  const int lane = tid & 63;
  const int wid  = tid >> 6;
  const int l15  = lane & 15;
  const int l4   = lane >> 4;

  // XCD swizzle (bijective: nwg % 8 == 0 for all our grids)
  const int nwg = (int)(gridDim.x * gridDim.y);
  int bid = (int)(blockIdx.y * gridDim.x + blockIdx.x);
  int swz = (bid & 7) * (nwg >> 3) + (bid >> 3);
  const int m0 = (swz / (int)gridDim.x) * 128;
  const int n0 = (swz % (int)gridDim.x) * 128;

  const int wr = (wid >> 1) * 64;
  const int wc = (wid & 1) * 64;
  const int srow = tid >> 3;
  const int scol = (tid & 7) * 8;

  f32x4 acc[4][4] = {};

  const short* Ab = A + (size_t)(m0 + srow) * K + scol;
  const short* Wb = W + (size_t)(n0 + srow) * K + scol;

  for (int k0 = 0; k0 < K; k0 += 64) {
#pragma unroll
    for (int i = 0; i < 4; ++i) {
      GLD16(Ab + (size_t)(i * 32) * K + k0, &As[(i * 32 + wid * 8) * 64]);
      GLD16(Wb + (size_t)(i * 32) * K + k0, &Ws[(i * 32 + wid * 8) * 64]);
    }
    __syncthreads();

#pragma unroll
    for (int kk = 0; kk < 2; ++kk) {
      bf16x8 af[4], wf[4];
#pragma unroll
      for (int m = 0; m < 4; ++m)
        af[m] = *(const bf16x8*)&As[(wr + m * 16 + l15) * 64 + kk * 32 + l4 * 8];
#pragma unroll
      for (int n = 0; n < 4; ++n)
        wf[n] = *(const bf16x8*)&Ws[(wc + n * 16 + l15) * 64 + kk * 32 + l4 * 8];
#pragma unroll
      for (int m = 0; m < 4; ++m)
#pragma unroll
        for (int n = 0; n < 4; ++n)
          acc[m][n] = __builtin_amdgcn_mfma_f32_16x16x32_bf16(af[m], wf[n], acc[m][n], 0, 0, 0);
    }
    __syncthreads();
  }

  float* Cb = (n0 < splitN) ? C1 : (C2 - splitN);
#pragma unroll
  for (int m = 0; m < 4; ++m) {
    int rbase = m0 + wr + m * 16 + l4 * 4;
#pragma unroll
    for (int n = 0; n < 4; ++n) {
      int cbase = n0 + wc + n * 16 + l15;
#pragma unroll
      for (int r = 0; r < 4; ++r)
        Cb[(size_t)(rbase + r) * ldc + cbase] = sf(acc[m][n][r]);
    }
  }
}

// ---------------------------------------------------------------------------
// RoPE
// ---------------------------------------------------------------------------
__device__ __forceinline__ void rope8(const float* in, float* out,
                                      const float* fc, const float* fs, int t, int p0)
{
  f32x4 a = *(const f32x4*)in;
  f32x4 b = *(const f32x4*)(in + 4);
  f32x4 cv = *(const f32x4*)&fc[t * 64 + p0];
  f32x4 sv = *(const f32x4*)&fs[t * 64 + p0];
  float x0[8] = {a[0], a[1], a[2], a[3], b[0], b[1], b[2], b[3]};
#pragma unroll
  for (int i = 0; i < 4; ++i) {
    float xr = x0[2 * i], xi = x0[2 * i + 1];
    out[2 * i]     = sf(xr * cv[i] - xi * sv[i]);
    out[2 * i + 1] = sf(xr * sv[i] + xi * cv[i]);
  }
}

// Q: f32 [2048][4096] -> bf16 q_bf, pre-scaled by QSCALE
__global__ __launch_bounds__(256) void rope_q_bf(
    const float* __restrict__ q, short* __restrict__ qb,
    const float* __restrict__ fc, const float* __restrict__ fs)
{
  size_t idx = ((size_t)blockIdx.x * 256 + threadIdx.x) * 8;
  int t   = (int)(idx >> 12);
  int col = (int)(idx & 4095);
  float o[8];
  rope8(&q[idx], o, fc, fs, t, (col & 127) >> 1);
  short8_t ob;
#pragma unroll
  for (int i = 0; i < 8; ++i) ob[i] = f2b(o[i] * QSCALE);
  *(short8_t*)&qb[idx] = ob;
}

// K: cache_k f32 in-place + bf16 copy (unscaled)
__global__ __launch_bounds__(256) void rope_k_dual(
    float* __restrict__ ck, short* __restrict__ kb,
    const float* __restrict__ fc, const float* __restrict__ fs)
{
  size_t idx = ((size_t)blockIdx.x * 256 + threadIdx.x) * 8;
  int t   = (int)(idx >> 10);
  int col = (int)(idx & 1023);
  float o[8];
  rope8(&ck[idx], o, fc, fs, t, (col & 127) >> 1);
  *(f32x4*)&ck[idx]     = f32x4{o[0], o[1], o[2], o[3]};
  *(f32x4*)&ck[idx + 4] = f32x4{o[4], o[5], o[6], o[7]};
  short8_t ob;
#pragma unroll
  for (int i = 0; i < 8; ++i) ob[i] = f2b(o[i]);
  *(short8_t*)&kb[idx] = ob;
}

// cache_v f32 [2048][8*128] -> Vt bf16 [8][128][2048]
__global__ __launch_bounds__(256) void transpose_v(
    const float* __restrict__ cv, short* __restrict__ Vt)
{
  __shared__ short tile[64][72];
  const int t0 = blockIdx.x * 64;
  const int d0 = blockIdx.y * 64;
  const int h  = blockIdx.z;
  const int tid = threadIdx.x;
  const int r = tid >> 3;
  const int c = (tid & 7) * 8;
#pragma unroll
  for (int it = 0; it < 2; ++it) {
    short8_t v = cvt8(&cv[(size_t)(t0 + it * 32 + r) * 1024 + h * 128 + d0 + c]);
    *(short8_t*)&tile[it * 32 + r][c] = v;
  }
  __syncthreads();
#pragma unroll
  for (int it = 0; it < 2; ++it) {
    int dr = it * 32 + r;
    short8_t v;
#pragma unroll
    for (int i = 0; i < 8; ++i) v[i] = tile[c + i][dr];
    *(short8_t*)&Vt[(size_t)(h * 128 + d0 + dr) * SEQLEN + t0 + c] = v;
  }
}

// ---------------------------------------------------------------------------
// Causal flash attention, swapped-QK^T 32x32 MFMA, single-wave blocks.
// Grid: 2048 blocks x 64 threads; flat id -> (qrank, head), qtile = 63-qrank
// (heavy-first dispatch). Each wave: 32 q-rows, KV tiles of 64 keys.
// Lane state: q = lane&31, S^T keys = crow(r,hi) = (r&3)+8*(r>>2)+4*hi.
// P staged through wave-private LDS [q][key], pad 88 (4-way banks).
// ---------------------------------------------------------------------------
__global__ __launch_bounds__(64) void attn_fwd2(
    const short* __restrict__ Q,    // [2048][4096] bf16, pre-scaled
    const short* __restrict__ Kc,   // [2048][1024] bf16
    const short* __restrict__ Vt,   // [8][128][2048] bf16
    short* __restrict__ O)          // [2048][4096] bf16
{
  const int h   = (int)blockIdx.x & 31;
  const int qt  = 63 - ((int)blockIdx.x >> 5);   // heavy first
  const int kvh = h >> 2;
  const int lane = threadIdx.x & 63;
  const int l31 = lane & 31;
  const int hi  = lane >> 5;

  __shared__ short P_lds[32][88];   // [q][key 0..63], cols 64..87 pad
  __shared__ float exch[32];

  const int q0 = qt * 32;
  const int qg = q0 + l31;

  // Q B-frags (loop-invariant): k = ks*16 + hi*8
  bf16x8 qf[8];
  {
    const short* qp = Q + (size_t)qg * 4096 + h * 128 + hi * 8;
#pragma unroll
    for (int ks = 0; ks < 8; ++ks) qf[ks] = *(const bf16x8*)(qp + ks * 16);
  }

  f32x16 o0 = {}, o1 = {}, o2 = {}, o3 = {};
  float m = -1e30f, l = 0.f;

  const int kend = q0 + 32;
  for (int kt = 0; kt < kend; kt += 64) {
    // S^T = K * Q^T (two 32-key tiles)
    f32x16 s0 = {}, s1 = {};
    {
      const short* kp = Kc + (size_t)(kt + l31) * 1024 + kvh * 128 + hi * 8;
      __builtin_amdgcn_s_setprio(1);
#pragma unroll
      for (int ks = 0; ks < 8; ++ks) {
        bf16x8 k0 = *(const bf16x8*)(kp + ks * 16);
        bf16x8 k1 = *(const bf16x8*)(kp + 32 * 1024 + ks * 16);
        s0 = __builtin_amdgcn_mfma_f32_32x32x16_bf16(k0, qf[ks], s0, 0, 0, 0);
        s1 = __builtin_amdgcn_mfma_f32_32x32x16_bf16(k1, qf[ks], s1, 0, 0, 0);
      }
      __builtin_amdgcn_s_setprio(0);
    }

    // causal mask (diagonal tile only)
    if (kt + 63 > q0) {
#pragma unroll
      for (int r = 0; r < 16; ++r) {
        int crow = (r & 3) + 8 * (r >> 2) + 4 * hi;
        if (kt + crow > qg)      s0[r] = -1e30f;
        if (kt + 32 + crow > qg) s1[r] = -1e30f;
      }
    }

    // per-q max over 64 keys: in-lane tree + cross-half shuffle
    float t[8];
#pragma unroll
    for (int r = 0; r < 8; ++r)
      t[r] = fmaxf(fmaxf(s0[r], s0[r + 8]), fmaxf(s1[r], s1[r + 8]));
    float pmax = fmaxf(fmaxf(fmaxf(t[0], t[1]), fmaxf(t[2], t[3])),
                       fmaxf(fmaxf(t[4], t[5]), fmaxf(t[6], t[7])));
    pmax = fmaxf(pmax, __shfl_xor(pmax, 32, 64));

    // defer-max (T13): rescale only when tile max grows past m+8
    if (!__all(pmax <= m + 8.f)) {
      float mnew = fmaxf(m, pmax);
      float resc = __expf(m - mnew);
      m = mnew;
      l *= resc;
      if (lane < 32) exch[l31] = resc;
#pragma unroll
      for (int r = 0; r < 16; ++r) {
        float rs = exch[(r & 3) + 8 * (r >> 2) + 4 * hi];
        o0[r] *= rs; o1[r] *= rs; o2[r] *= rs; o3[r] *= rs;
      }
    }

    // p = exp(s - m) in place, row sum
    float psum = 0.f;
#pragma unroll
    for (int r = 0; r < 16; ++r) { s0[r] = __expf(s0[r] - m); psum += s0[r]; }
#pragma unroll
    for (int r = 0; r < 16; ++r) { s1[r] = __expf(s1[r] - m); psum += s1[r]; }
    l += psum + __shfl_xor(psum, 32, 64);

    // P -> LDS [q][key]: quad r=4t..4t+3 = keys 8t+4hi..+3 (one b64 each)
#pragma unroll
    for (int t4 = 0; t4 < 4; ++t4) {
      int c = 8 * t4 + 4 * hi;
      *(uint2_t*)&P_lds[l31][c]      = uint2_t{pkb(s0[4*t4], s0[4*t4+1]), pkb(s0[4*t4+2], s0[4*t4+3])};
      *(uint2_t*)&P_lds[l31][32 + c] = uint2_t{pkb(s1[4*t4], s1[4*t4+1]), pkb(s1[4*t4+2], s1[4*t4+3])};
    }

    // PV: 4 x 16-key subtiles; A-frag = ds_read_b128 from P_lds
    const short* vb = Vt + (size_t)(kvh * 128 + l31) * SEQLEN + kt + hi * 8;
#pragma unroll
    for (int g = 0; g < 4; ++g) {
      bf16x8 pf = *(const bf16x8*)&P_lds[l31][g * 16 + hi * 8];
      const short* vg = vb + g * 16;
      __builtin_amdgcn_s_setprio(1);
      o0 = __builtin_amdgcn_mfma_f32_32x32x16_bf16(pf, *(const bf16x8*)(vg),                       o0, 0, 0, 0);
      o1 = __builtin_amdgcn_mfma_f32_32x32x16_bf16(pf, *(const bf16x8*)(vg + 32 * SEQLEN),         o1, 0, 0, 0);
      o2 = __builtin_amdgcn_mfma_f32_32x32x16_bf16(pf, *(const bf16x8*)(vg + 64 * SEQLEN),         o2, 0, 0, 0);
      o3 = __builtin_amdgcn_mfma_f32_32x32x16_bf16(pf, *(const bf16x8*)(vg + (size_t)96 * SEQLEN), o3, 0, 0, 0);
      __builtin_amdgcn_s_setprio(0);
    }
  }

  // normalize + store: row q = q0+crow(r,hi), col d = dtile*32 + l31
  if (lane < 32) exch[l31] = 1.f / l;
#pragma unroll
  for (int r = 0; r < 16; ++r) {
    int crow = (r & 3) + 8 * (r >> 2) + 4 * hi;
    float inv = exch[crow];
    short* ob = O + (size_t)(q0 + crow) * 4096 + h * 128 + l31;
    ob[0]  = f2b(o0[r] * inv);
    ob[32] = f2b(o1[r] * inv);
    ob[64] = f2b(o2[r] * inv);
    ob[96] = f2b(o3[r] * inv);
  }
}

// ---------------------------------------------------------------------------
extern "C" void kernel_launch(void* const* d_in, const int* in_sizes, int n_in,
                              void* d_out, int out_size, void* d_ws, size_t ws_size,
                              hipStream_t stream) {
  const float* x  = (const float*)d_in[0];
  const float* wq = (const float*)d_in[1];
  const float* wk = (const float*)d_in[2];
  const float* wv = (const float*)d_in[3];
  const float* wo = (const float*)d_in[4];
  const float* fc = (const float*)d_in[5];
  const float* fs = (const float*)d_in[6];

  float* out = (float*)d_out;
  float* out_main = out;                               // [2048][4096]
  float* cache_k  = out + (size_t)2048 * 4096;         // [4096][8][128]
  float* cache_v  = cache_k + (size_t)4096 * 8 * 128;  // [4096][8][128]

  const size_t MB_W = 33554432;   // 4096x4096 bf16
  const size_t MB_X = 16777216;   // 2048x4096 bf16
  // ws (>= 54.6 MB, confirmed R5):
  // slotA [0, 33.5MB): w_bf  /  q_bf + k_bf during attn
  // slotB [33.5, 50.3MB): x_bf  /  attn_out
  // slotC [50.3, 54.5MB): Vt
  short* slotA = (short*)d_ws;
  short* x_bf  = (short*)((char*)d_ws + MB_W);
  short* attn_out = x_bf;
  short* Vt    = (short*)((char*)d_ws + MB_W + MB_X);
  short* q_bf  = slotA;
  short* k_bf  = slotA + (size_t)2048 * 4096;

  // converts + projections
  cvt_bf16<<<4096, 256, 0, stream>>>(x, x_bf);
  cvt_bf16<<<8192, 256, 0, stream>>>(wq, slotA);
  gemm_bf<<<dim3(32, 16), 256, 0, stream>>>(x_bf, slotA, out_main, out_main, 4096, 4096, 1 << 30);
  cvt_bf16<<<2048, 256, 0, stream>>>(wk, slotA);
  cvt_bf16<<<2048, 256, 0, stream>>>(wv, slotA + (size_t)1024 * 4096);
  gemm_bf<<<dim3(16, 16), 256, 0, stream>>>(x_bf, slotA, cache_k, cache_v, 4096, 1024, 1024);

  // RoPE + V transpose + cache tail zeros
  rope_q_bf<<<4096, 256, 0, stream>>>(out_main, q_bf, fc, fs);
  rope_k_dual<<<1024, 256, 0, stream>>>(cache_k, k_bf, fc, fs);
  transpose_v<<<dim3(32, 2, 8), 256, 0, stream>>>(cache_v, Vt);
  hipMemsetAsync(cache_k + (size_t)2048 * 1024, 0, (size_t)2048 * 1024 * 4, stream);
  hipMemsetAsync(cache_v + (size_t)2048 * 1024, 0, (size_t)2048 * 1024 * 4, stream);

  // attention: 2048 single-wave blocks, heavy qtiles first
  attn_fwd2<<<2048, 64, 0, stream>>>(q_bf, k_bf, Vt, attn_out);

  // output projection
  cvt_bf16<<<8192, 256, 0, stream>>>(wo, slotA);
  gemm_bf<<<dim3(32, 16), 256, 0, stream>>>(attn_out, slotA, out_main, out_main, 4096, 4096, 1 << 30);
}